// Round 5
// baseline (47012.753 us; speedup 1.0000x reference)
//
#include <hip/hip_runtime.h>
#include <math.h>

#define T_Q   2000
#define N_M   100000
#define D_DIM 1024
#define NC    8     // candidate superset per query

typedef float f32x4 __attribute__((ext_vector_type(4)));

__device__ __forceinline__ bool better(float av, int ai, float bv, int bi) {
    return (av > bv) || (av == bv && ai < bi);
}

// One block (4 waves) per query. Wave-per-row fp32 scan -> per-wave top-8 ->
// block top-8 -> fp64 rescore -> top-k -> synth average. No workspace.
__global__ __launch_bounds__(256)
void knn_all(const float* __restrict__ Qm, const float* __restrict__ Mm,
             const float* __restrict__ Sm, const int* __restrict__ topk_p,
             float* __restrict__ outp)
{
    __shared__ float  qs[D_DIM];
    __shared__ float  wv[4][NC];
    __shared__ int    wi[4][NC];
    __shared__ int    cand8[NC];
    __shared__ double dval[NC];
    __shared__ int    chosen[NC];
    __shared__ int    sk;

    const int q    = blockIdx.x;
    const int tid  = threadIdx.x;
    const int wid  = tid >> 6;
    const int lane = tid & 63;

    // stage the query row in LDS (coalesced)
    for (int i = tid; i < D_DIM / 4; i += 256)
        ((f32x4*)qs)[i] = ((const f32x4*)(Qm + (size_t)q * D_DIM))[i];
    __syncthreads();

    // ---- fp32 scan: each wave owns rows r = wid, wid+4, ... ----
    float tv[NC]; int ti[NC];
#pragma unroll
    for (int k = 0; k < NC; ++k) { tv[k] = -INFINITY; ti[k] = 0; }

    for (int r = wid; r < N_M; r += 4) {
        const f32x4* mp = (const f32x4*)(Mm + (size_t)r * D_DIM) + lane * 4;
        const f32x4* qp = (const f32x4*)qs + lane * 4;
        float dot = 0.f, ss = 0.f;
#pragma unroll
        for (int j = 0; j < 4; ++j) {
            f32x4 mv = mp[j], qv = qp[j];
#pragma unroll
            for (int u = 0; u < 4; ++u) { dot += mv[u] * qv[u]; ss += mv[u] * mv[u]; }
        }
#pragma unroll
        for (int off = 1; off <= 32; off <<= 1) {
            dot += __shfl_xor(dot, off, 64);
            ss  += __shfl_xor(ss,  off, 64);
        }
        float s = ss > 0.f ? dot * rsqrtf(ss) : -INFINITY;
        if (better(s, r, tv[NC - 1], ti[NC - 1])) {
            float cv = s; int ci = r;
#pragma unroll
            for (int k = 0; k < NC; ++k) {
                bool b = better(cv, ci, tv[k], ti[k]);
                float nv = b ? cv : tv[k]; int ni = b ? ci : ti[k];
                float ov = b ? tv[k] : cv; int oi = b ? ti[k] : ci;
                tv[k] = nv; ti[k] = ni; cv = ov; ci = oi;
            }
        }
    }

    // all 64 lanes of a wave hold identical lists (shfl_xor allreduce)
    if (lane == 0)
#pragma unroll
        for (int k = 0; k < NC; ++k) { wv[wid][k] = tv[k]; wi[wid][k] = ti[k]; }
    __syncthreads();

    // ---- merge 4 waves' lists -> block top-8 (fp32 ranking) ----
    if (tid == 0) {
        unsigned used = 0;
        for (int j = 0; j < NC; ++j) {
            float bv = -INFINITY; int bi = 0; int bs = -1;
            for (int s = 0; s < 4 * NC; ++s) {
                if (used & (1u << s)) continue;
                float v = wv[s >> 3][s & 7]; int i = wi[s >> 3][s & 7];
                if (bs < 0 || better(v, i, bv, bi)) { bv = v; bi = i; bs = s; }
            }
            used |= 1u << bs;
            cand8[j] = bi;
        }
        int kk = *topk_p;
        if (kk < 1) kk = 1;
        if (kk > NC) kk = NC;
        sk = kk;
    }
    __syncthreads();

    // ---- fp64 rescore of the 8 candidates (wave wid handles ci=wid, wid+4) ----
    for (int ci = wid; ci < NC; ci += 4) {
        int idx = cand8[ci];
        if (idx < 0)     idx = 0;
        if (idx >= N_M)  idx = N_M - 1;
        const f32x4* mp = (const f32x4*)(Mm + (size_t)idx * D_DIM) + lane * 4;
        const f32x4* qp = (const f32x4*)qs + lane * 4;
        double dot = 0.0, ss = 0.0;
#pragma unroll
        for (int j = 0; j < 4; ++j) {
            f32x4 mv = mp[j], qv = qp[j];
#pragma unroll
            for (int u = 0; u < 4; ++u) {
                dot += (double)mv[u] * (double)qv[u];
                ss  += (double)mv[u] * (double)mv[u];
            }
        }
#pragma unroll
        for (int off = 1; off <= 32; off <<= 1) {
            dot += __shfl_xor(dot, off, 64);
            ss  += __shfl_xor(ss, off, 64);
        }
        if (lane == 0) dval[ci] = ss > 0.0 ? dot / sqrt(ss) : -1e300;
    }
    __syncthreads();

    // ---- exact top-k of the 8 by fp64 score ----
    if (tid == 0) {
        int kk = sk;
        unsigned used = 0;
        for (int j = 0; j < kk; ++j) {
            int best = -1;
            for (int i = 0; i < NC; ++i) {
                if (used & (1u << i)) continue;
                if (best < 0 || dval[i] > dval[best] ||
                    (dval[i] == dval[best] && cand8[i] < cand8[best])) best = i;
            }
            used |= 1u << best;
            chosen[j] = cand8[best];
        }
    }
    __syncthreads();

    // ---- gather-average of synth rows ----
    const int kk = sk;
    const int d0 = tid * 4;
    f32x4 a; a[0] = 0.f; a[1] = 0.f; a[2] = 0.f; a[3] = 0.f;
    for (int j = 0; j < kk; ++j) {
        f32x4 s4 = *(const f32x4*)(Sm + (size_t)chosen[j] * D_DIM + d0);
        a = a + s4;
    }
    const float inv = 1.0f / (float)kk;
    a = a * inv;
    *(f32x4*)(outp + (size_t)q * D_DIM + d0) = a;
}

extern "C" void kernel_launch(void* const* d_in, const int* in_sizes, int n_in,
                              void* d_out, int out_size, void* d_ws, size_t ws_size,
                              hipStream_t stream)
{
    (void)in_sizes; (void)n_in; (void)out_size; (void)d_ws; (void)ws_size;

    const float* Qm   = (const float*)d_in[0];
    const float* Mm   = (const float*)d_in[1];
    const float* Sm   = (const float*)d_in[2];
    const int*   topk = (const int*)d_in[3];
    float*       outp = (float*)d_out;

    hipLaunchKernelGGL(knn_all, dim3(T_Q), dim3(256), 0, stream,
                       Qm, Mm, Sm, topk, outp);
}

// Round 6
// 3238.882 us; speedup vs baseline: 14.5151x; 14.5151x over previous
//
#include <hip/hip_runtime.h>
#include <math.h>

#define T_Q    2000
#define N_M    100000
#define D_DIM  1024
#define QTILES 16
#define NTILES 782          // ceil(100000/128)
#define BK     32
#define KSTEPS (D_DIM / BK) // 32
#define LDH    40           // A/B LDS row stride in halves (80 B)
#define SDH    136          // score LDS row stride in halves (272 B)
#define NC     16           // rescore candidate superset per query
#define QPAD   2048

typedef _Float16 f16x8 __attribute__((ext_vector_type(8)));
typedef float    f32x4 __attribute__((ext_vector_type(4)));

struct __align__(8) Cand { float v; int i; };
static_assert(sizeof(Cand) == 8, "cand size");

__device__ __forceinline__ bool better(float av, int ai, float bv, int bi) {
    return (av > bv) || (av == bv && ai < bi);
}

__device__ __forceinline__ f32x4 zero4() {
    f32x4 z; z[0] = 0.f; z[1] = 0.f; z[2] = 0.f; z[3] = 0.f; return z;
}

// ---------------------------------------------------------------------------
// Kernel 0: inverse L2 norms of M rows. One wave per row (proven pattern).
// ---------------------------------------------------------------------------
__global__ __launch_bounds__(256)
void knn_norms(const float* __restrict__ Mm, float* __restrict__ invn)
{
    const int wid  = threadIdx.x >> 6;
    const int lane = threadIdx.x & 63;
    const int r    = blockIdx.x * 4 + wid;
    if (r >= N_M) return;
    const f32x4* mp = (const f32x4*)(Mm + (size_t)r * D_DIM) + lane * 4;
    float ss = 0.f;
#pragma unroll
    for (int j = 0; j < 4; ++j) {
        f32x4 v = mp[j];
#pragma unroll
        for (int u = 0; u < 4; ++u) ss += v[u] * v[u];
    }
#pragma unroll
    for (int off = 1; off <= 32; off <<= 1) ss += __shfl_xor(ss, off, 64);
    if (lane == 0) invn[r] = ss > 0.f ? rsqrtf(ss) : 0.f;
}

// ---------------------------------------------------------------------------
// Kernel 1: fp16 MFMA scores (normalized-M rows x raw-Q cols). Scores go to
// an LDS tile; 128 scan threads keep a running per-query top-16. No shuffle
// networks, no fused select in the K loop, outer loops not unrolled.
// ---------------------------------------------------------------------------
__global__ __launch_bounds__(256)
void knn_gemm_select(const float* __restrict__ Qm, const float* __restrict__ Mm,
                     const float* __restrict__ invn, Cand* __restrict__ cand,
                     int tpbn, int nsuper)
{
    __shared__ _Float16 As[128][LDH];   // 10240 B
    __shared__ _Float16 Bs[128][LDH];   // 10240 B
    __shared__ _Float16 Ss[128][SDH];   // 34816 B  (total 55296 B)

    const int qtile = blockIdx.x & (QTILES - 1);
    const int sup   = blockIdx.x >> 4;
    const int nt0   = sup * tpbn;
    int nt1 = nt0 + tpbn;
    if (nt1 > NTILES) nt1 = NTILES;

    const int tid = threadIdx.x;
    const int row = tid >> 1;       // 0..127
    const int kh  = tid & 1;        // 16-float half of the BK=32 slab

    const int qrow_g = qtile * 128 + row;
    const bool b_ok  = qrow_g < T_Q;
    const float* bbase = Qm + (size_t)qrow_g * D_DIM + kh * 16;

    const int lane = tid & 63;
    const int wid  = tid >> 6;
    const int wr   = wid >> 1;      // row half of the 128x128 tile
    const int wc   = wid & 1;       // col half
    const int l15  = lane & 15;
    const int lg   = lane >> 4;

    float rv[NC]; int ri[NC];
#pragma unroll
    for (int k = 0; k < NC; ++k) { rv[k] = -INFINITY; ri[k] = 0; }

#pragma unroll 1
    for (int ntile = nt0; ntile < nt1; ++ntile) {
        const int nrow_g = ntile * 128 + row;
        const bool a_ok  = nrow_g < N_M;
        const float* abase = Mm + (size_t)nrow_g * D_DIM + kh * 16;
        const float ainv = a_ok ? invn[nrow_g] : 0.f;

        f32x4 acc[4][4];
#pragma unroll
        for (int i = 0; i < 4; ++i)
#pragma unroll
            for (int j = 0; j < 4; ++j) acc[i][j] = zero4();

        f32x4 ar[4], br[4];
#pragma unroll
        for (int i = 0; i < 4; ++i) {
            ar[i] = a_ok ? ((const f32x4*)abase)[i] : zero4();
            br[i] = b_ok ? ((const f32x4*)bbase)[i] : zero4();
        }

#pragma unroll 1
        for (int t = 0; t < KSTEPS; ++t) {
            __syncthreads();   // previous readers of As/Bs (and prev scan) done

            f16x8 ha0, ha1, hb0, hb1;
#pragma unroll
            for (int i = 0; i < 2; ++i)
#pragma unroll
                for (int j = 0; j < 4; ++j) {
                    ha0[i * 4 + j] = (_Float16)(ar[i][j] * ainv);
                    ha1[i * 4 + j] = (_Float16)(ar[i + 2][j] * ainv);
                    hb0[i * 4 + j] = (_Float16)(br[i][j]);
                    hb1[i * 4 + j] = (_Float16)(br[i + 2][j]);
                }
            *(f16x8*)&As[row][kh * 16]     = ha0;
            *(f16x8*)&As[row][kh * 16 + 8] = ha1;
            *(f16x8*)&Bs[row][kh * 16]     = hb0;
            *(f16x8*)&Bs[row][kh * 16 + 8] = hb1;

            __syncthreads();   // writes visible

            if (t + 1 < KSTEPS) {
                const float* ap = abase + (t + 1) * BK;
                const float* bp = bbase + (t + 1) * BK;
#pragma unroll
                for (int i = 0; i < 4; ++i) {
                    ar[i] = a_ok ? ((const f32x4*)ap)[i] : zero4();
                    br[i] = b_ok ? ((const f32x4*)bp)[i] : zero4();
                }
            }

            f16x8 af[4], bf[4];
#pragma unroll
            for (int f = 0; f < 4; ++f) {
                af[f] = *(const f16x8*)&As[wr * 64 + f * 16 + l15][lg * 8];
                bf[f] = *(const f16x8*)&Bs[wc * 64 + f * 16 + l15][lg * 8];
            }
#pragma unroll
            for (int i = 0; i < 4; ++i)
#pragma unroll
                for (int j = 0; j < 4; ++j)
                    acc[i][j] = __builtin_amdgcn_mfma_f32_16x16x32_f16(
                        af[i], bf[j], acc[i][j], 0, 0, 0);
        }

        // dump scores to LDS: Ss[row_in_tile][qcol_in_tile]
#pragma unroll
        for (int fr = 0; fr < 4; ++fr)
#pragma unroll
            for (int fc = 0; fc < 4; ++fc)
#pragma unroll
                for (int r = 0; r < 4; ++r)
                    Ss[wr * 64 + fr * 16 + lg * 4 + r][wc * 64 + fc * 16 + l15] =
                        (_Float16)acc[fr][fc][r];
        __syncthreads();

        // 128 scan threads: fold this tile's 128 scores for own query column
        if (tid < 128) {
#pragma unroll 1
            for (int r = 0; r < 128; ++r) {
                const int ng = ntile * 128 + r;
                float s = (ng < N_M) ? (float)Ss[r][tid] : -INFINITY;
                if (better(s, ng, rv[NC - 1], ri[NC - 1])) {
                    float cv = s; int ci = ng;
#pragma unroll
                    for (int k = 0; k < NC; ++k) {
                        bool b = better(cv, ci, rv[k], ri[k]);
                        float nv = b ? cv : rv[k]; int ni = b ? ci : ri[k];
                        float ov = b ? rv[k] : cv; int oi = b ? ri[k] : ci;
                        rv[k] = nv; ri[k] = ni; cv = ov; ci = oi;
                    }
                }
            }
        }
        // next iteration's first barrier separates this scan from LDS reuse
    }

    if (tid < 128) {
        const int qg = qtile * 128 + tid;
        Cand* dst = cand + ((size_t)qg * nsuper + sup) * NC;
#pragma unroll
        for (int k = 0; k < NC; ++k) { Cand c; c.v = rv[k]; c.i = ri[k]; dst[k] = c; }
    }
}

// ---------------------------------------------------------------------------
// Kernel 2: per query, reduce nsuper*16 candidates to global approx top-16.
// One wave per query; sequential lane-0 merge (no shuffle networks).
// ---------------------------------------------------------------------------
__global__ __launch_bounds__(64)
void knn_top16(const Cand* __restrict__ cand, int* __restrict__ top_idx, int ncand)
{
    __shared__ float lv[64][NC];
    __shared__ int   li[64][NC];

    const int q = blockIdx.x;
    const int lane = threadIdx.x;
    const Cand* rowp = cand + (size_t)q * ncand;

    float tv[NC]; int ti[NC];
#pragma unroll
    for (int k = 0; k < NC; ++k) { tv[k] = -INFINITY; ti[k] = 0; }

#pragma unroll 1
    for (int e = lane; e < ncand; e += 64) {
        Cand c = rowp[e];
        if (better(c.v, c.i, tv[NC - 1], ti[NC - 1])) {
            float cv = c.v; int ci = c.i;
#pragma unroll
            for (int k = 0; k < NC; ++k) {
                bool b = better(cv, ci, tv[k], ti[k]);
                float nv = b ? cv : tv[k]; int ni = b ? ci : ti[k];
                float ov = b ? tv[k] : cv; int oi = b ? ti[k] : ci;
                tv[k] = nv; ti[k] = ni; cv = ov; ci = oi;
            }
        }
    }

#pragma unroll
    for (int k = 0; k < NC; ++k) { lv[lane][k] = tv[k]; li[lane][k] = ti[k]; }
    __syncthreads();

    if (lane == 0) {
#pragma unroll 1
        for (int l = 1; l < 64; ++l) {
#pragma unroll 1
            for (int k = 0; k < NC; ++k) {
                float v = lv[l][k]; int i = li[l][k];
                if (!better(v, i, tv[NC - 1], ti[NC - 1])) break; // lists sorted desc
                float cv = v; int ci = i;
#pragma unroll
                for (int kk = 0; kk < NC; ++kk) {
                    bool b = better(cv, ci, tv[kk], ti[kk]);
                    float nv = b ? cv : tv[kk]; int ni = b ? ci : ti[kk];
                    float ov = b ? tv[kk] : cv; int oi = b ? ti[kk] : ci;
                    tv[kk] = nv; ti[kk] = ni; cv = ov; ci = oi;
                }
            }
        }
#pragma unroll
        for (int k = 0; k < NC; ++k) top_idx[q * NC + k] = ti[k];
    }
}

// ---------------------------------------------------------------------------
// Kernel 3: exact fp64 rescore of the 16 candidates, top-k, gather-average.
// ---------------------------------------------------------------------------
__global__ __launch_bounds__(256)
void knn_rescore(const float* __restrict__ Qm, const float* __restrict__ Mm,
                 const float* __restrict__ Sm, const int* __restrict__ topk_p,
                 const int* __restrict__ top_idx, float* __restrict__ outp)
{
    const int q   = blockIdx.x;
    const int tid = threadIdx.x;
    const int wid = tid >> 6, lane = tid & 63;

    __shared__ double sval[NC];
    __shared__ int    sidx[NC];
    __shared__ int    chosen[NC];

    int k = *topk_p;
    if (k > NC) k = NC;
    if (k < 1)  k = 1;

    const float* qrow = Qm + (size_t)q * D_DIM;
#pragma unroll 1
    for (int ci = wid; ci < NC; ci += 4) {
        int idx = top_idx[q * NC + ci];
        if (idx < 0)    idx = 0;
        if (idx >= N_M) idx = N_M - 1;
        const f32x4* mp = (const f32x4*)(Mm + (size_t)idx * D_DIM) + lane * 4;
        const f32x4* qp = (const f32x4*)qrow + lane * 4;
        double dot = 0.0, ss = 0.0;
#pragma unroll
        for (int j = 0; j < 4; ++j) {
            f32x4 mv = mp[j], qv = qp[j];
#pragma unroll
            for (int u = 0; u < 4; ++u) {
                dot += (double)mv[u] * (double)qv[u];
                ss  += (double)mv[u] * (double)mv[u];
            }
        }
#pragma unroll
        for (int off = 1; off <= 32; off <<= 1) {
            dot += __shfl_xor(dot, off, 64);
            ss  += __shfl_xor(ss, off, 64);
        }
        if (lane == 0) { sval[ci] = ss > 0.0 ? dot / sqrt(ss) : -1e300; sidx[ci] = idx; }
    }
    __syncthreads();

    if (tid == 0) {
        unsigned used = 0;
        for (int j = 0; j < k; ++j) {
            int best = -1;
            for (int i = 0; i < NC; ++i) {
                if (used & (1u << i)) continue;
                if (best < 0 || sval[i] > sval[best] ||
                    (sval[i] == sval[best] && sidx[i] < sidx[best])) best = i;
            }
            used |= 1u << best;
            chosen[j] = sidx[best];
        }
    }
    __syncthreads();

    const int d0 = tid * 4;
    f32x4 a = zero4();
    for (int j = 0; j < k; ++j) {
        f32x4 s4 = *(const f32x4*)(Sm + (size_t)chosen[j] * D_DIM + d0);
        a = a + s4;
    }
    const float inv = 1.0f / (float)k;
    a = a * inv;
    *(f32x4*)(outp + (size_t)q * D_DIM + d0) = a;
}

// ---------------------------------------------------------------------------
// Fallback: round-5 kernel, verbatim (proven passed, absmax 0.0, 47 ms).
// ---------------------------------------------------------------------------
#define FNC 8
__global__ __launch_bounds__(256)
void knn_all(const float* __restrict__ Qm, const float* __restrict__ Mm,
             const float* __restrict__ Sm, const int* __restrict__ topk_p,
             float* __restrict__ outp)
{
    __shared__ float  qs[D_DIM];
    __shared__ float  wv[4][FNC];
    __shared__ int    wi[4][FNC];
    __shared__ int    cand8[FNC];
    __shared__ double dval[FNC];
    __shared__ int    chosen[FNC];
    __shared__ int    sk;

    const int q    = blockIdx.x;
    const int tid  = threadIdx.x;
    const int wid  = tid >> 6;
    const int lane = tid & 63;

    for (int i = tid; i < D_DIM / 4; i += 256)
        ((f32x4*)qs)[i] = ((const f32x4*)(Qm + (size_t)q * D_DIM))[i];
    __syncthreads();

    float tv[FNC]; int ti[FNC];
#pragma unroll
    for (int k = 0; k < FNC; ++k) { tv[k] = -INFINITY; ti[k] = 0; }

    for (int r = wid; r < N_M; r += 4) {
        const f32x4* mp = (const f32x4*)(Mm + (size_t)r * D_DIM) + lane * 4;
        const f32x4* qp = (const f32x4*)qs + lane * 4;
        float dot = 0.f, ss = 0.f;
#pragma unroll
        for (int j = 0; j < 4; ++j) {
            f32x4 mv = mp[j], qv = qp[j];
#pragma unroll
            for (int u = 0; u < 4; ++u) { dot += mv[u] * qv[u]; ss += mv[u] * mv[u]; }
        }
#pragma unroll
        for (int off = 1; off <= 32; off <<= 1) {
            dot += __shfl_xor(dot, off, 64);
            ss  += __shfl_xor(ss,  off, 64);
        }
        float s = ss > 0.f ? dot * rsqrtf(ss) : -INFINITY;
        if (better(s, r, tv[FNC - 1], ti[FNC - 1])) {
            float cv = s; int ci = r;
#pragma unroll
            for (int k = 0; k < FNC; ++k) {
                bool b = better(cv, ci, tv[k], ti[k]);
                float nv = b ? cv : tv[k]; int ni = b ? ci : ti[k];
                float ov = b ? tv[k] : cv; int oi = b ? ti[k] : ci;
                tv[k] = nv; ti[k] = ni; cv = ov; ci = oi;
            }
        }
    }

    if (lane == 0)
#pragma unroll
        for (int k = 0; k < FNC; ++k) { wv[wid][k] = tv[k]; wi[wid][k] = ti[k]; }
    __syncthreads();

    if (tid == 0) {
        unsigned used = 0;
        for (int j = 0; j < FNC; ++j) {
            float bv = -INFINITY; int bi = 0; int bs = -1;
            for (int s = 0; s < 4 * FNC; ++s) {
                if (used & (1u << s)) continue;
                float v = wv[s >> 3][s & 7]; int i = wi[s >> 3][s & 7];
                if (bs < 0 || better(v, i, bv, bi)) { bv = v; bi = i; bs = s; }
            }
            used |= 1u << bs;
            cand8[j] = bi;
        }
        int kk = *topk_p;
        if (kk < 1) kk = 1;
        if (kk > FNC) kk = FNC;
        sk = kk;
    }
    __syncthreads();

    for (int ci = wid; ci < FNC; ci += 4) {
        int idx = cand8[ci];
        if (idx < 0)     idx = 0;
        if (idx >= N_M)  idx = N_M - 1;
        const f32x4* mp = (const f32x4*)(Mm + (size_t)idx * D_DIM) + lane * 4;
        const f32x4* qp = (const f32x4*)qs + lane * 4;
        double dot = 0.0, ss = 0.0;
#pragma unroll
        for (int j = 0; j < 4; ++j) {
            f32x4 mv = mp[j], qv = qp[j];
#pragma unroll
            for (int u = 0; u < 4; ++u) {
                dot += (double)mv[u] * (double)qv[u];
                ss  += (double)mv[u] * (double)mv[u];
            }
        }
#pragma unroll
        for (int off = 1; off <= 32; off <<= 1) {
            dot += __shfl_xor(dot, off, 64);
            ss  += __shfl_xor(ss, off, 64);
        }
        if (lane == 0) dval[ci] = ss > 0.0 ? dot / sqrt(ss) : -1e300;
    }
    __syncthreads();

    if (tid == 0) {
        int kk = sk;
        unsigned used = 0;
        for (int j = 0; j < kk; ++j) {
            int best = -1;
            for (int i = 0; i < FNC; ++i) {
                if (used & (1u << i)) continue;
                if (best < 0 || dval[i] > dval[best] ||
                    (dval[i] == dval[best] && cand8[i] < cand8[best])) best = i;
            }
            used |= 1u << best;
            chosen[j] = cand8[best];
        }
    }
    __syncthreads();

    const int kk = sk;
    const int d0 = tid * 4;
    f32x4 a = zero4();
    for (int j = 0; j < kk; ++j) {
        f32x4 s4 = *(const f32x4*)(Sm + (size_t)chosen[j] * D_DIM + d0);
        a = a + s4;
    }
    const float inv = 1.0f / (float)kk;
    a = a * inv;
    *(f32x4*)(outp + (size_t)q * D_DIM + d0) = a;
}

// ---------------------------------------------------------------------------
extern "C" void kernel_launch(void* const* d_in, const int* in_sizes, int n_in,
                              void* d_out, int out_size, void* d_ws, size_t ws_size,
                              hipStream_t stream)
{
    (void)in_sizes; (void)n_in; (void)out_size;

    const float* Qm   = (const float*)d_in[0];
    const float* Mm   = (const float*)d_in[1];
    const float* Sm   = (const float*)d_in[2];
    const int*   topk = (const int*)d_in[3];
    float*       outp = (float*)d_out;

    const size_t inv_bytes = ((size_t)N_M * sizeof(float) + 511) & ~(size_t)511;
    const size_t ti_bytes  = (((size_t)T_Q * NC * sizeof(int)) + 511) & ~(size_t)511;
    const size_t per_sup   = (size_t)QPAD * NC * sizeof(Cand);   // 256 KiB

    long long avail = (long long)ws_size - (long long)(inv_bytes + ti_bytes);
    int ns = avail > 0 ? (int)(avail / (long long)per_sup) : 0;
    if (ns > 64) ns = 64;

    if (ns < 1 || d_ws == nullptr) {
        hipLaunchKernelGGL(knn_all, dim3(T_Q), dim3(256), 0, stream,
                           Qm, Mm, Sm, topk, outp);
        return;
    }

    int tpbn = (NTILES + ns - 1) / ns;
    ns = (NTILES + tpbn - 1) / tpbn;

    float* invn  = (float*)d_ws;
    int* top_idx = (int*)((char*)d_ws + inv_bytes);
    Cand*  cand  = (Cand*)((char*)d_ws + inv_bytes + ti_bytes);

    hipLaunchKernelGGL(knn_norms, dim3((N_M + 3) / 4), dim3(256), 0, stream,
                       Mm, invn);
    hipLaunchKernelGGL(knn_gemm_select, dim3(QTILES * ns), dim3(256), 0, stream,
                       Qm, Mm, invn, cand, tpbn, ns);
    hipLaunchKernelGGL(knn_top16, dim3(T_Q), dim3(64), 0, stream,
                       cand, top_idx, ns * NC);
    hipLaunchKernelGGL(knn_rescore, dim3(T_Q), dim3(256), 0, stream,
                       Qm, Mm, Sm, topk, top_idx, outp);
}

// Round 7
// 2971.398 us; speedup vs baseline: 15.8218x; 1.0900x over previous
//
#include <hip/hip_runtime.h>
#include <math.h>

#define T_Q    2000
#define N_M    100000
#define D_DIM  1024
#define QTILES 16
#define NTILES 782          // ceil(100000/128)
#define BK     32
#define KSTEPS (D_DIM / BK) // 32
#define LDH    40           // A/B LDS row stride in halves (80 B)
#define SSW    72           // transposed score tile row stride in halves (144 B)
#define NC     16           // rescore candidate superset per query
#define QPAD   2048

typedef _Float16 f16x8 __attribute__((ext_vector_type(8)));
typedef _Float16 f16x4 __attribute__((ext_vector_type(4)));
typedef float    f32x4 __attribute__((ext_vector_type(4)));

struct __align__(8) Cand { float v; int i; };
static_assert(sizeof(Cand) == 8, "cand size");

__device__ __forceinline__ bool better(float av, int ai, float bv, int bi) {
    return (av > bv) || (av == bv && ai < bi);
}

__device__ __forceinline__ f32x4 zero4() {
    f32x4 z; z[0] = 0.f; z[1] = 0.f; z[2] = 0.f; z[3] = 0.f; return z;
}

// ---------------------------------------------------------------------------
// Kernel Q: convert query matrix to fp16 once (rows >= T_Q zero-filled).
// ---------------------------------------------------------------------------
__global__ __launch_bounds__(256)
void knn_qcvt(const float* __restrict__ Qm, _Float16* __restrict__ Qh)
{
    const size_t base = (size_t)blockIdx.x * 2048 + (size_t)threadIdx.x * 8;
    const int row = (int)(base >> 10);
    f16x8 h;
    if (row < T_Q) {
        f32x4 a = *(const f32x4*)(Qm + base);
        f32x4 b = *(const f32x4*)(Qm + base + 4);
#pragma unroll
        for (int j = 0; j < 4; ++j) { h[j] = (_Float16)a[j]; h[4 + j] = (_Float16)b[j]; }
    } else {
#pragma unroll
        for (int j = 0; j < 8; ++j) h[j] = (_Float16)0.f;
    }
    *(f16x8*)(Qh + base) = h;
}

// ---------------------------------------------------------------------------
// Kernel 0: inverse L2 norms of M rows. One wave per row.
// ---------------------------------------------------------------------------
__global__ __launch_bounds__(256)
void knn_norms(const float* __restrict__ Mm, float* __restrict__ invn)
{
    const int wid  = threadIdx.x >> 6;
    const int lane = threadIdx.x & 63;
    const int r    = blockIdx.x * 4 + wid;
    if (r >= N_M) return;
    const f32x4* mp = (const f32x4*)(Mm + (size_t)r * D_DIM) + lane * 4;
    float ss = 0.f;
#pragma unroll
    for (int j = 0; j < 4; ++j) {
        f32x4 v = mp[j];
#pragma unroll
        for (int u = 0; u < 4; ++u) ss += v[u] * v[u];
    }
#pragma unroll
    for (int off = 1; off <= 32; off <<= 1) ss += __shfl_xor(ss, off, 64);
    if (lane == 0) invn[r] = ss > 0.f ? rsqrtf(ss) : 0.f;
}

// ---------------------------------------------------------------------------
// Kernel 1: fp16 MFMA scores (raw-M rows x fp16-Q cols); transposed LDS score
// dump in two 64-row halves; vectorized scan keeps per-query top-16 with
// norm scaling applied at scan time.
// ---------------------------------------------------------------------------
__global__ __launch_bounds__(256)
void knn_gemm_select(const _Float16* __restrict__ Qh, const float* __restrict__ Mm,
                     const float* __restrict__ invn, Cand* __restrict__ cand,
                     int tpbn, int nsuper)
{
    __shared__ _Float16 As[128][LDH];   // 10240 B
    __shared__ _Float16 Bs[128][LDH];   // 10240 B
    __shared__ _Float16 Ss[128][SSW];   // 18432 B (transposed: [qcol][row-in-half])
    __shared__ float    sinv[128];      //   512 B   -> total 39424 B

    const int qtile = blockIdx.x & (QTILES - 1);
    const int sup   = blockIdx.x >> 4;
    const int nt0   = sup * tpbn;
    int nt1 = nt0 + tpbn;
    if (nt1 > NTILES) nt1 = NTILES;

    const int tid = threadIdx.x;
    const int row = tid >> 1;       // 0..127
    const int kh  = tid & 1;        // 16-element half of the BK=32 slab

    const int qrow_g = qtile * 128 + row;
    const _Float16* bbase = Qh + (size_t)qrow_g * D_DIM + kh * 16;

    const int lane = tid & 63;
    const int wid  = tid >> 6;
    const int wr   = wid >> 1;      // row half of the 128x128 tile
    const int wc   = wid & 1;       // col half
    const int l15  = lane & 15;
    const int lg   = lane >> 4;

    float rv[NC]; int ri[NC];
#pragma unroll
    for (int k = 0; k < NC; ++k) { rv[k] = -INFINITY; ri[k] = 0; }

#pragma unroll 1
    for (int ntile = nt0; ntile < nt1; ++ntile) {
        const int nrow_g = ntile * 128 + row;
        const bool a_ok  = nrow_g < N_M;
        const float* abase = Mm + (size_t)nrow_g * D_DIM + kh * 16;

        f32x4 acc[4][4];
#pragma unroll
        for (int i = 0; i < 4; ++i)
#pragma unroll
            for (int j = 0; j < 4; ++j) acc[i][j] = zero4();

        f32x4 ar[4];
        f16x8 brh[2];
#pragma unroll
        for (int i = 0; i < 4; ++i) ar[i] = a_ok ? ((const f32x4*)abase)[i] : zero4();
        brh[0] = *(const f16x8*)(bbase);
        brh[1] = *(const f16x8*)(bbase + 8);

#pragma unroll 1
        for (int t = 0; t < KSTEPS; ++t) {
            __syncthreads();   // previous readers of As/Bs done

            f16x8 ha0, ha1;
#pragma unroll
            for (int i = 0; i < 2; ++i)
#pragma unroll
                for (int j = 0; j < 4; ++j) {
                    ha0[i * 4 + j] = (_Float16)ar[i][j];
                    ha1[i * 4 + j] = (_Float16)ar[i + 2][j];
                }
            *(f16x8*)&As[row][kh * 16]     = ha0;
            *(f16x8*)&As[row][kh * 16 + 8] = ha1;
            *(f16x8*)&Bs[row][kh * 16]     = brh[0];
            *(f16x8*)&Bs[row][kh * 16 + 8] = brh[1];

            __syncthreads();   // writes visible

            if (t + 1 < KSTEPS) {
                const float*    ap = abase + (t + 1) * BK;
                const _Float16* bp = bbase + (t + 1) * BK;
#pragma unroll
                for (int i = 0; i < 4; ++i) ar[i] = a_ok ? ((const f32x4*)ap)[i] : zero4();
                brh[0] = *(const f16x8*)(bp);
                brh[1] = *(const f16x8*)(bp + 8);
            }

            f16x8 af[4], bf[4];
#pragma unroll
            for (int f = 0; f < 4; ++f) {
                af[f] = *(const f16x8*)&As[wr * 64 + f * 16 + l15][lg * 8];
                bf[f] = *(const f16x8*)&Bs[wc * 64 + f * 16 + l15][lg * 8];
            }
#pragma unroll
            for (int i = 0; i < 4; ++i)
#pragma unroll
                for (int j = 0; j < 4; ++j)
                    acc[i][j] = __builtin_amdgcn_mfma_f32_16x16x32_f16(
                        af[i], bf[j], acc[i][j], 0, 0, 0);
        }

        // stage this tile's inverse norms (consumed by both scans)
        if (tid < 128) {
            const int r = ntile * 128 + tid;
            sinv[tid] = (r < N_M) ? invn[r] : 0.f;
        }

        // two half-tile dump+scan rounds: h=0 rows 0..63 (wr==0), h=1 rows 64..127
#pragma unroll 1
        for (int h = 0; h < 2; ++h) {
            __syncthreads();   // Ss free (scan of prev half / prev tile done); sinv ready
            if (wr == h) {
#pragma unroll
                for (int fr = 0; fr < 4; ++fr)
#pragma unroll
                    for (int fc = 0; fc < 4; ++fc) {
                        f16x4 v;
#pragma unroll
                        for (int r = 0; r < 4; ++r) v[r] = (_Float16)acc[fr][fc][r];
                        *(f16x4*)&Ss[wc * 64 + fc * 16 + l15][fr * 16 + lg * 4] = v;
                    }
            }
            __syncthreads();   // dump visible

            if (tid < 128) {
                const int base = ntile * 128 + h * 64;
                int nval = N_M - base;
                if (nval > 64) nval = 64;
#pragma unroll 1
                for (int c = 0; c < nval; c += 8) {
                    f16x8 sv = *(const f16x8*)&Ss[tid][c];
                    f32x4 sa = *(const f32x4*)&sinv[h * 64 + c];
                    f32x4 sb = *(const f32x4*)&sinv[h * 64 + c + 4];
                    const int lim = (nval - c >= 8) ? 8 : (nval - c);
                    float s[8];
#pragma unroll
                    for (int j = 0; j < 4; ++j) {
                        s[j]     = (float)sv[j] * sa[j];
                        s[4 + j] = (float)sv[4 + j] * sb[j];
                    }
                    if (lim < 8)
#pragma unroll
                        for (int j = 0; j < 8; ++j)
                            if (j >= lim) s[j] = -INFINITY;
                    float m01 = fmaxf(s[0], s[1]), m23 = fmaxf(s[2], s[3]);
                    float m45 = fmaxf(s[4], s[5]), m67 = fmaxf(s[6], s[7]);
                    float mx = fmaxf(fmaxf(m01, m23), fmaxf(m45, m67));
                    if (mx >= rv[NC - 1]) {
#pragma unroll 1
                        for (int j = 0; j < 8; ++j) {
                            if (j >= lim) break;
                            float cv = s[j]; int ci = base + c + j;
                            if (better(cv, ci, rv[NC - 1], ri[NC - 1])) {
#pragma unroll
                                for (int k = 0; k < NC; ++k) {
                                    bool b = better(cv, ci, rv[k], ri[k]);
                                    float nv = b ? cv : rv[k]; int ni = b ? ci : ri[k];
                                    float ov = b ? rv[k] : cv; int oi = b ? ri[k] : ci;
                                    rv[k] = nv; ri[k] = ni; cv = ov; ci = oi;
                                }
                            }
                        }
                    }
                }
            }
        }
    }

    if (tid < 128) {
        const int qg = qtile * 128 + tid;
        Cand* dst = cand + ((size_t)qg * nsuper + sup) * NC;
#pragma unroll
        for (int k = 0; k < NC; ++k) { Cand c; c.v = rv[k]; c.i = ri[k]; dst[k] = c; }
    }
}

// ---------------------------------------------------------------------------
// Kernel 2: per query, reduce nsuper*16 candidates to global approx top-16.
// ---------------------------------------------------------------------------
__global__ __launch_bounds__(64)
void knn_top16(const Cand* __restrict__ cand, int* __restrict__ top_idx, int ncand)
{
    __shared__ float lv[64][NC];
    __shared__ int   li[64][NC];

    const int q = blockIdx.x;
    const int lane = threadIdx.x;
    const Cand* rowp = cand + (size_t)q * ncand;

    float tv[NC]; int ti[NC];
#pragma unroll
    for (int k = 0; k < NC; ++k) { tv[k] = -INFINITY; ti[k] = 0; }

#pragma unroll 1
    for (int e = lane; e < ncand; e += 64) {
        Cand c = rowp[e];
        if (better(c.v, c.i, tv[NC - 1], ti[NC - 1])) {
            float cv = c.v; int ci = c.i;
#pragma unroll
            for (int k = 0; k < NC; ++k) {
                bool b = better(cv, ci, tv[k], ti[k]);
                float nv = b ? cv : tv[k]; int ni = b ? ci : ti[k];
                float ov = b ? tv[k] : cv; int oi = b ? ti[k] : ci;
                tv[k] = nv; ti[k] = ni; cv = ov; ci = oi;
            }
        }
    }

#pragma unroll
    for (int k = 0; k < NC; ++k) { lv[lane][k] = tv[k]; li[lane][k] = ti[k]; }
    __syncthreads();

    if (lane == 0) {
#pragma unroll 1
        for (int l = 1; l < 64; ++l) {
#pragma unroll 1
            for (int k = 0; k < NC; ++k) {
                float v = lv[l][k]; int i = li[l][k];
                if (!better(v, i, tv[NC - 1], ti[NC - 1])) break; // lists sorted desc
                float cv = v; int ci = i;
#pragma unroll
                for (int kk = 0; kk < NC; ++kk) {
                    bool b = better(cv, ci, tv[kk], ti[kk]);
                    float nv = b ? cv : tv[kk]; int ni = b ? ci : ti[kk];
                    float ov = b ? tv[kk] : cv; int oi = b ? ti[kk] : ci;
                    tv[kk] = nv; ti[kk] = ni; cv = ov; ci = oi;
                }
            }
        }
#pragma unroll
        for (int k = 0; k < NC; ++k) top_idx[q * NC + k] = ti[k];
    }
}

// ---------------------------------------------------------------------------
// Kernel 3: exact fp64 rescore of the 16 candidates, top-k, gather-average.
// ---------------------------------------------------------------------------
__global__ __launch_bounds__(256)
void knn_rescore(const float* __restrict__ Qm, const float* __restrict__ Mm,
                 const float* __restrict__ Sm, const int* __restrict__ topk_p,
                 const int* __restrict__ top_idx, float* __restrict__ outp)
{
    const int q   = blockIdx.x;
    const int tid = threadIdx.x;
    const int wid = tid >> 6, lane = tid & 63;

    __shared__ double sval[NC];
    __shared__ int    sidx[NC];
    __shared__ int    chosen[NC];

    int k = *topk_p;
    if (k > NC) k = NC;
    if (k < 1)  k = 1;

    const float* qrow = Qm + (size_t)q * D_DIM;
#pragma unroll 1
    for (int ci = wid; ci < NC; ci += 4) {
        int idx = top_idx[q * NC + ci];
        if (idx < 0)    idx = 0;
        if (idx >= N_M) idx = N_M - 1;
        const f32x4* mp = (const f32x4*)(Mm + (size_t)idx * D_DIM) + lane * 4;
        const f32x4* qp = (const f32x4*)qrow + lane * 4;
        double dot = 0.0, ss = 0.0;
#pragma unroll
        for (int j = 0; j < 4; ++j) {
            f32x4 mv = mp[j], qv = qp[j];
#pragma unroll
            for (int u = 0; u < 4; ++u) {
                dot += (double)mv[u] * (double)qv[u];
                ss  += (double)mv[u] * (double)mv[u];
            }
        }
#pragma unroll
        for (int off = 1; off <= 32; off <<= 1) {
            dot += __shfl_xor(dot, off, 64);
            ss  += __shfl_xor(ss, off, 64);
        }
        if (lane == 0) { sval[ci] = ss > 0.0 ? dot / sqrt(ss) : -1e300; sidx[ci] = idx; }
    }
    __syncthreads();

    if (tid == 0) {
        unsigned used = 0;
        for (int j = 0; j < k; ++j) {
            int best = -1;
            for (int i = 0; i < NC; ++i) {
                if (used & (1u << i)) continue;
                if (best < 0 || sval[i] > sval[best] ||
                    (sval[i] == sval[best] && sidx[i] < sidx[best])) best = i;
            }
            used |= 1u << best;
            chosen[j] = sidx[best];
        }
    }
    __syncthreads();

    const int d0 = tid * 4;
    f32x4 a = zero4();
    for (int j = 0; j < k; ++j) {
        f32x4 s4 = *(const f32x4*)(Sm + (size_t)chosen[j] * D_DIM + d0);
        a = a + s4;
    }
    const float inv = 1.0f / (float)k;
    a = a * inv;
    *(f32x4*)(outp + (size_t)q * D_DIM + d0) = a;
}

// ---------------------------------------------------------------------------
// Fallback: round-5 kernel, verbatim (proven: passed, absmax 0.0).
// ---------------------------------------------------------------------------
#define FNC 8
__global__ __launch_bounds__(256)
void knn_all(const float* __restrict__ Qm, const float* __restrict__ Mm,
             const float* __restrict__ Sm, const int* __restrict__ topk_p,
             float* __restrict__ outp)
{
    __shared__ float  qs[D_DIM];
    __shared__ float  wv[4][FNC];
    __shared__ int    wi[4][FNC];
    __shared__ int    cand8[FNC];
    __shared__ double dval[FNC];
    __shared__ int    chosen[FNC];
    __shared__ int    sk;

    const int q    = blockIdx.x;
    const int tid  = threadIdx.x;
    const int wid  = tid >> 6;
    const int lane = tid & 63;

    for (int i = tid; i < D_DIM / 4; i += 256)
        ((f32x4*)qs)[i] = ((const f32x4*)(Qm + (size_t)q * D_DIM))[i];
    __syncthreads();

    float tv[FNC]; int ti[FNC];
#pragma unroll
    for (int k = 0; k < FNC; ++k) { tv[k] = -INFINITY; ti[k] = 0; }

    for (int r = wid; r < N_M; r += 4) {
        const f32x4* mp = (const f32x4*)(Mm + (size_t)r * D_DIM) + lane * 4;
        const f32x4* qp = (const f32x4*)qs + lane * 4;
        float dot = 0.f, ss = 0.f;
#pragma unroll
        for (int j = 0; j < 4; ++j) {
            f32x4 mv = mp[j], qv = qp[j];
#pragma unroll
            for (int u = 0; u < 4; ++u) { dot += mv[u] * qv[u]; ss += mv[u] * mv[u]; }
        }
#pragma unroll
        for (int off = 1; off <= 32; off <<= 1) {
            dot += __shfl_xor(dot, off, 64);
            ss  += __shfl_xor(ss,  off, 64);
        }
        float s = ss > 0.f ? dot * rsqrtf(ss) : -INFINITY;
        if (better(s, r, tv[FNC - 1], ti[FNC - 1])) {
            float cv = s; int ci = r;
#pragma unroll
            for (int k = 0; k < FNC; ++k) {
                bool b = better(cv, ci, tv[k], ti[k]);
                float nv = b ? cv : tv[k]; int ni = b ? ci : ti[k];
                float ov = b ? tv[k] : cv; int oi = b ? ti[k] : ci;
                tv[k] = nv; ti[k] = ni; cv = ov; ci = oi;
            }
        }
    }

    if (lane == 0)
#pragma unroll
        for (int k = 0; k < FNC; ++k) { wv[wid][k] = tv[k]; wi[wid][k] = ti[k]; }
    __syncthreads();

    if (tid == 0) {
        unsigned used = 0;
        for (int j = 0; j < FNC; ++j) {
            float bv = -INFINITY; int bi = 0; int bs = -1;
            for (int s = 0; s < 4 * FNC; ++s) {
                if (used & (1u << s)) continue;
                float v = wv[s >> 3][s & 7]; int i = wi[s >> 3][s & 7];
                if (bs < 0 || better(v, i, bv, bi)) { bv = v; bi = i; bs = s; }
            }
            used |= 1u << bs;
            cand8[j] = bi;
        }
        int kk = *topk_p;
        if (kk < 1) kk = 1;
        if (kk > FNC) kk = FNC;
        sk = kk;
    }
    __syncthreads();

    for (int ci = wid; ci < FNC; ci += 4) {
        int idx = cand8[ci];
        if (idx < 0)     idx = 0;
        if (idx >= N_M)  idx = N_M - 1;
        const f32x4* mp = (const f32x4*)(Mm + (size_t)idx * D_DIM) + lane * 4;
        const f32x4* qp = (const f32x4*)qs + lane * 4;
        double dot = 0.0, ss = 0.0;
#pragma unroll
        for (int j = 0; j < 4; ++j) {
            f32x4 mv = mp[j], qv = qp[j];
#pragma unroll
            for (int u = 0; u < 4; ++u) {
                dot += (double)mv[u] * (double)qv[u];
                ss  += (double)mv[u] * (double)mv[u];
            }
        }
#pragma unroll
        for (int off = 1; off <= 32; off <<= 1) {
            dot += __shfl_xor(dot, off, 64);
            ss  += __shfl_xor(ss, off, 64);
        }
        if (lane == 0) dval[ci] = ss > 0.0 ? dot / sqrt(ss) : -1e300;
    }
    __syncthreads();

    if (tid == 0) {
        int kk = sk;
        unsigned used = 0;
        for (int j = 0; j < kk; ++j) {
            int best = -1;
            for (int i = 0; i < FNC; ++i) {
                if (used & (1u << i)) continue;
                if (best < 0 || dval[i] > dval[best] ||
                    (dval[i] == dval[best] && cand8[i] < cand8[best])) best = i;
            }
            used |= 1u << best;
            chosen[j] = cand8[best];
        }
    }
    __syncthreads();

    const int kk = sk;
    const int d0 = tid * 4;
    f32x4 a = zero4();
    for (int j = 0; j < kk; ++j) {
        f32x4 s4 = *(const f32x4*)(Sm + (size_t)chosen[j] * D_DIM + d0);
        a = a + s4;
    }
    const float inv = 1.0f / (float)kk;
    a = a * inv;
    *(f32x4*)(outp + (size_t)q * D_DIM + d0) = a;
}

// ---------------------------------------------------------------------------
extern "C" void kernel_launch(void* const* d_in, const int* in_sizes, int n_in,
                              void* d_out, int out_size, void* d_ws, size_t ws_size,
                              hipStream_t stream)
{
    (void)in_sizes; (void)n_in; (void)out_size;

    const float* Qm   = (const float*)d_in[0];
    const float* Mm   = (const float*)d_in[1];
    const float* Sm   = (const float*)d_in[2];
    const int*   topk = (const int*)d_in[3];
    float*       outp = (float*)d_out;

    const size_t inv_bytes = ((size_t)N_M * sizeof(float) + 511) & ~(size_t)511;      // 400384
    const size_t qh_bytes  = (size_t)QPAD * D_DIM * sizeof(_Float16);                 // 4 MiB
    const size_t ti_bytes  = (((size_t)T_Q * NC * sizeof(int)) + 511) & ~(size_t)511; // 128000
    const size_t per_sup   = (size_t)QPAD * NC * sizeof(Cand);                        // 256 KiB

    long long avail = (long long)ws_size - (long long)(inv_bytes + qh_bytes + ti_bytes);
    int ns = avail > 0 ? (int)(avail / (long long)per_sup) : 0;
    if (ns > 64) ns = 64;

    if (ns < 1 || d_ws == nullptr) {
        hipLaunchKernelGGL(knn_all, dim3(T_Q), dim3(256), 0, stream,
                           Qm, Mm, Sm, topk, outp);
        return;
    }

    int tpbn = (NTILES + ns - 1) / ns;
    ns = (NTILES + tpbn - 1) / tpbn;

    float*    invn    = (float*)d_ws;
    _Float16* Qh      = (_Float16*)((char*)d_ws + inv_bytes);
    int*      top_idx = (int*)((char*)d_ws + inv_bytes + qh_bytes);
    Cand*     cand    = (Cand*)((char*)d_ws + inv_bytes + qh_bytes + ti_bytes);

    hipLaunchKernelGGL(knn_qcvt, dim3(QPAD * D_DIM / 2048), dim3(256), 0, stream,
                       Qm, Qh);
    hipLaunchKernelGGL(knn_norms, dim3((N_M + 3) / 4), dim3(256), 0, stream,
                       Mm, invn);
    hipLaunchKernelGGL(knn_gemm_select, dim3(QTILES * ns), dim3(256), 0, stream,
                       Qh, Mm, invn, cand, tpbn, ns);
    hipLaunchKernelGGL(knn_top16, dim3(T_Q), dim3(64), 0, stream,
                       cand, top_idx, ns * NC);
    hipLaunchKernelGGL(knn_rescore, dim3(T_Q), dim3(256), 0, stream,
                       Qm, Mm, Sm, topk, top_idx, outp);
}

// Round 8
// 2864.490 us; speedup vs baseline: 16.4123x; 1.0373x over previous
//
#include <hip/hip_runtime.h>
#include <math.h>

#define T_Q    2000
#define N_M    100000
#define D_DIM  1024
#define QTILES 16
#define NTILES 782          // ceil(100000/128)
#define MPAD   (NTILES * 128)   // 100096 zero-padded fp16 M rows
#define BK     32
#define KSTEPS (D_DIM / BK) // 32
#define LDH    40           // middle-path A/B LDS row stride in halves (80 B)
#define SSW    72           // score tile row stride in halves (144 B)
#define NC     16           // rescore candidate superset per query
#define QPAD   2048

typedef _Float16 f16x8 __attribute__((ext_vector_type(8)));
typedef _Float16 f16x4 __attribute__((ext_vector_type(4)));
typedef float    f32x4 __attribute__((ext_vector_type(4)));
typedef unsigned int u32;

struct __align__(8) Cand { float v; int i; };
static_assert(sizeof(Cand) == 8, "cand size");

__device__ __forceinline__ bool better(float av, int ai, float bv, int bi) {
    return (av > bv) || (av == bv && ai < bi);
}

__device__ __forceinline__ f32x4 zero4() {
    f32x4 z; z[0] = 0.f; z[1] = 0.f; z[2] = 0.f; z[3] = 0.f; return z;
}

// async global->LDS, 16 B per lane (dest must be wave-uniform base + lane*16)
__device__ __forceinline__ void gload16(const _Float16* g, _Float16* l) {
    const __attribute__((address_space(1))) u32* gp =
        (const __attribute__((address_space(1))) u32*)g;
    __attribute__((address_space(3))) u32* lp =
        (__attribute__((address_space(3))) u32*)l;
    __builtin_amdgcn_global_load_lds(gp, lp, 16, 0, 0);
}

// ---------------------------------------------------------------------------
// Kernel Q: convert query matrix to fp16 once (rows >= T_Q zero-filled).
// ---------------------------------------------------------------------------
__global__ __launch_bounds__(256)
void knn_qcvt(const float* __restrict__ Qm, _Float16* __restrict__ Qh)
{
    const size_t base = (size_t)blockIdx.x * 2048 + (size_t)threadIdx.x * 8;
    const int row = (int)(base >> 10);
    f16x8 h;
    if (row < T_Q) {
        f32x4 a = *(const f32x4*)(Qm + base);
        f32x4 b = *(const f32x4*)(Qm + base + 4);
#pragma unroll
        for (int j = 0; j < 4; ++j) { h[j] = (_Float16)a[j]; h[4 + j] = (_Float16)b[j]; }
    } else {
#pragma unroll
        for (int j = 0; j < 8; ++j) h[j] = (_Float16)0.f;
    }
    *(f16x8*)(Qh + base) = h;
}

// ---------------------------------------------------------------------------
// Kernel M: fused norm + prescale + fp16 convert + zero-pad of M.
// One wave per row; rows >= N_M write zeros.
// ---------------------------------------------------------------------------
__global__ __launch_bounds__(256)
void knn_mcvt(const float* __restrict__ Mm, _Float16* __restrict__ Mh)
{
    const int wid  = threadIdx.x >> 6;
    const int lane = threadIdx.x & 63;
    const int r    = blockIdx.x * 4 + wid;   // grid covers MPAD rows
    f16x8 h0, h1;
    if (r < N_M) {
        const f32x4* mp = (const f32x4*)(Mm + (size_t)r * D_DIM) + lane * 4;
        f32x4 v0 = mp[0], v1 = mp[1], v2 = mp[2], v3 = mp[3];
        float ss = 0.f;
#pragma unroll
        for (int u = 0; u < 4; ++u)
            ss += v0[u] * v0[u] + v1[u] * v1[u] + v2[u] * v2[u] + v3[u] * v3[u];
#pragma unroll
        for (int off = 1; off <= 32; off <<= 1) ss += __shfl_xor(ss, off, 64);
        const float inv = ss > 0.f ? rsqrtf(ss) : 0.f;
#pragma unroll
        for (int u = 0; u < 4; ++u) {
            h0[u]     = (_Float16)(v0[u] * inv);
            h0[4 + u] = (_Float16)(v1[u] * inv);
            h1[u]     = (_Float16)(v2[u] * inv);
            h1[4 + u] = (_Float16)(v3[u] * inv);
        }
    } else {
#pragma unroll
        for (int j = 0; j < 8; ++j) { h0[j] = (_Float16)0.f; h1[j] = (_Float16)0.f; }
    }
    _Float16* dst = Mh + (size_t)r * D_DIM + lane * 16;
    *(f16x8*)dst       = h0;
    *(f16x8*)(dst + 8) = h1;
}

// ---------------------------------------------------------------------------
// Kernel 1 (main): fp16 MFMA scores via global_load_lds staging. M rows are
// norm-prescaled and zero-padded, so no conversion and no bounds checks in
// the K-loop. Select epilogue: LDS score dump + 128-thread scan (proven).
// ---------------------------------------------------------------------------
__global__ __launch_bounds__(256)
void knn_gemm_select_h(const _Float16* __restrict__ Qh,
                       const _Float16* __restrict__ Mh,
                       Cand* __restrict__ cand, int tpbn, int nsuper)
{
    __shared__ _Float16 As[128][32];    //  8192 B
    __shared__ _Float16 Bs[128][32];    //  8192 B
    __shared__ _Float16 Ss[128][SSW];   // 18432 B  (total 34816 B)

    const int qtile = blockIdx.x & (QTILES - 1);
    const int sup   = blockIdx.x >> 4;
    const int nt0   = sup * tpbn;
    int nt1 = nt0 + tpbn;
    if (nt1 > NTILES) nt1 = NTILES;

    const int tid  = threadIdx.x;
    const int lane = tid & 63;
    const int wid  = tid >> 6;
    const int wr   = wid >> 1;
    const int wc   = wid & 1;
    const int l15  = lane & 15;
    const int lg   = lane >> 4;

    // staging geometry: thread t covers 16 B at LDS linear offset t*16
    const int arow = tid >> 2;          // 0..63
    const int acol = (tid & 3) * 8;     // halves

    _Float16* Adst0 = &As[arow][acol];
    _Float16* Adst1 = &As[64 + arow][acol];
    _Float16* Bdst0 = &Bs[arow][acol];
    _Float16* Bdst1 = &Bs[64 + arow][acol];

    const _Float16* Bb = Qh + ((size_t)(qtile * 128 + arow) << 10) + acol;

    float rv[NC]; int ri[NC];
#pragma unroll
    for (int k = 0; k < NC; ++k) { rv[k] = -INFINITY; ri[k] = 0; }

#pragma unroll 1
    for (int ntile = nt0; ntile < nt1; ++ntile) {
        const _Float16* Ab = Mh + ((size_t)(ntile * 128 + arow) << 10) + acol;

        f32x4 acc[4][4];
#pragma unroll
        for (int i = 0; i < 4; ++i)
#pragma unroll
            for (int j = 0; j < 4; ++j) acc[i][j] = zero4();

#pragma unroll 1
        for (int t = 0; t < KSTEPS; ++t) {
            const int k0 = t * BK;
            gload16(Ab + k0, Adst0);
            gload16(Ab + k0 + (64 << 10), Adst1);
            gload16(Bb + k0, Bdst0);
            gload16(Bb + k0 + (64 << 10), Bdst1);

            __syncthreads();   // drains vmcnt -> staged data visible

            f16x8 af[4], bf[4];
#pragma unroll
            for (int f = 0; f < 4; ++f) {
                af[f] = *(const f16x8*)&As[wr * 64 + f * 16 + l15][lg * 8];
                bf[f] = *(const f16x8*)&Bs[wc * 64 + f * 16 + l15][lg * 8];
            }
#pragma unroll
            for (int i = 0; i < 4; ++i)
#pragma unroll
                for (int j = 0; j < 4; ++j)
                    acc[i][j] = __builtin_amdgcn_mfma_f32_16x16x32_f16(
                        af[i], bf[j], acc[i][j], 0, 0, 0);

            __syncthreads();   // readers done before next-step staging
        }

        // two half-tile dump+scan rounds (scores already normalized)
#pragma unroll 1
        for (int h = 0; h < 2; ++h) {
            __syncthreads();   // Ss free (previous scan finished)
            if (wr == h) {
#pragma unroll
                for (int fr = 0; fr < 4; ++fr)
#pragma unroll
                    for (int fc = 0; fc < 4; ++fc) {
                        f16x4 v;
#pragma unroll
                        for (int r = 0; r < 4; ++r) v[r] = (_Float16)acc[fr][fc][r];
                        *(f16x4*)&Ss[wc * 64 + fc * 16 + l15][fr * 16 + lg * 4] = v;
                    }
            }
            __syncthreads();   // dump visible

            if (tid < 128) {
                const int base = ntile * 128 + h * 64;
                int nval = N_M - base;
                if (nval > 64) nval = 64;
#pragma unroll 1
                for (int c = 0; c < nval; c += 8) {
                    f16x8 sv = *(const f16x8*)&Ss[tid][c];
                    const int lim = (nval - c >= 8) ? 8 : (nval - c);
                    float s[8];
#pragma unroll
                    for (int j = 0; j < 8; ++j) s[j] = (float)sv[j];
                    if (lim < 8)
#pragma unroll
                        for (int j = 0; j < 8; ++j)
                            if (j >= lim) s[j] = -INFINITY;
                    float m01 = fmaxf(s[0], s[1]), m23 = fmaxf(s[2], s[3]);
                    float m45 = fmaxf(s[4], s[5]), m67 = fmaxf(s[6], s[7]);
                    float mx = fmaxf(fmaxf(m01, m23), fmaxf(m45, m67));
                    if (mx >= rv[NC - 1]) {
#pragma unroll 1
                        for (int j = 0; j < 8; ++j) {
                            if (j >= lim) break;
                            float cv = s[j]; int ci = base + c + j;
                            if (better(cv, ci, rv[NC - 1], ri[NC - 1])) {
#pragma unroll
                                for (int k = 0; k < NC; ++k) {
                                    bool b = better(cv, ci, rv[k], ri[k]);
                                    float nv = b ? cv : rv[k]; int ni = b ? ci : ri[k];
                                    float ov = b ? rv[k] : cv; int oi = b ? ri[k] : ci;
                                    rv[k] = nv; ri[k] = ni; cv = ov; ci = oi;
                                }
                            }
                        }
                    }
                }
            }
        }
    }

    if (tid < 128) {
        const int qg = qtile * 128 + tid;
        Cand* dst = cand + ((size_t)qg * nsuper + sup) * NC;
#pragma unroll
        for (int k = 0; k < NC; ++k) { Cand c; c.v = rv[k]; c.i = ri[k]; dst[k] = c; }
    }
}

// ---------------------------------------------------------------------------
// Kernel 0 (middle path): inverse L2 norms of M rows. One wave per row.
// ---------------------------------------------------------------------------
__global__ __launch_bounds__(256)
void knn_norms(const float* __restrict__ Mm, float* __restrict__ invn)
{
    const int wid  = threadIdx.x >> 6;
    const int lane = threadIdx.x & 63;
    const int r    = blockIdx.x * 4 + wid;
    if (r >= N_M) return;
    const f32x4* mp = (const f32x4*)(Mm + (size_t)r * D_DIM) + lane * 4;
    float ss = 0.f;
#pragma unroll
    for (int j = 0; j < 4; ++j) {
        f32x4 v = mp[j];
#pragma unroll
        for (int u = 0; u < 4; ++u) ss += v[u] * v[u];
    }
#pragma unroll
    for (int off = 1; off <= 32; off <<= 1) ss += __shfl_xor(ss, off, 64);
    if (lane == 0) invn[r] = ss > 0.f ? rsqrtf(ss) : 0.f;
}

// ---------------------------------------------------------------------------
// Kernel 1 (middle path, round-7 verbatim): fp32 M staged with conversion.
// ---------------------------------------------------------------------------
__global__ __launch_bounds__(256)
void knn_gemm_select(const _Float16* __restrict__ Qh, const float* __restrict__ Mm,
                     const float* __restrict__ invn, Cand* __restrict__ cand,
                     int tpbn, int nsuper)
{
    __shared__ _Float16 As[128][LDH];
    __shared__ _Float16 Bs[128][LDH];
    __shared__ _Float16 Ss[128][SSW];
    __shared__ float    sinv[128];

    const int qtile = blockIdx.x & (QTILES - 1);
    const int sup   = blockIdx.x >> 4;
    const int nt0   = sup * tpbn;
    int nt1 = nt0 + tpbn;
    if (nt1 > NTILES) nt1 = NTILES;

    const int tid = threadIdx.x;
    const int row = tid >> 1;
    const int kh  = tid & 1;

    const int qrow_g = qtile * 128 + row;
    const _Float16* bbase = Qh + (size_t)qrow_g * D_DIM + kh * 16;

    const int lane = tid & 63;
    const int wid  = tid >> 6;
    const int wr   = wid >> 1;
    const int wc   = wid & 1;
    const int l15  = lane & 15;
    const int lg   = lane >> 4;

    float rv[NC]; int ri[NC];
#pragma unroll
    for (int k = 0; k < NC; ++k) { rv[k] = -INFINITY; ri[k] = 0; }

#pragma unroll 1
    for (int ntile = nt0; ntile < nt1; ++ntile) {
        const int nrow_g = ntile * 128 + row;
        const bool a_ok  = nrow_g < N_M;
        const float* abase = Mm + (size_t)nrow_g * D_DIM + kh * 16;

        f32x4 acc[4][4];
#pragma unroll
        for (int i = 0; i < 4; ++i)
#pragma unroll
            for (int j = 0; j < 4; ++j) acc[i][j] = zero4();

        f32x4 ar[4];
        f16x8 brh[2];
#pragma unroll
        for (int i = 0; i < 4; ++i) ar[i] = a_ok ? ((const f32x4*)abase)[i] : zero4();
        brh[0] = *(const f16x8*)(bbase);
        brh[1] = *(const f16x8*)(bbase + 8);

#pragma unroll 1
        for (int t = 0; t < KSTEPS; ++t) {
            __syncthreads();

            f16x8 ha0, ha1;
#pragma unroll
            for (int i = 0; i < 2; ++i)
#pragma unroll
                for (int j = 0; j < 4; ++j) {
                    ha0[i * 4 + j] = (_Float16)ar[i][j];
                    ha1[i * 4 + j] = (_Float16)ar[i + 2][j];
                }
            *(f16x8*)&As[row][kh * 16]     = ha0;
            *(f16x8*)&As[row][kh * 16 + 8] = ha1;
            *(f16x8*)&Bs[row][kh * 16]     = brh[0];
            *(f16x8*)&Bs[row][kh * 16 + 8] = brh[1];

            __syncthreads();

            if (t + 1 < KSTEPS) {
                const float*    ap = abase + (t + 1) * BK;
                const _Float16* bp = bbase + (t + 1) * BK;
#pragma unroll
                for (int i = 0; i < 4; ++i) ar[i] = a_ok ? ((const f32x4*)ap)[i] : zero4();
                brh[0] = *(const f16x8*)(bp);
                brh[1] = *(const f16x8*)(bp + 8);
            }

            f16x8 af[4], bf[4];
#pragma unroll
            for (int f = 0; f < 4; ++f) {
                af[f] = *(const f16x8*)&As[wr * 64 + f * 16 + l15][lg * 8];
                bf[f] = *(const f16x8*)&Bs[wc * 64 + f * 16 + l15][lg * 8];
            }
#pragma unroll
            for (int i = 0; i < 4; ++i)
#pragma unroll
                for (int j = 0; j < 4; ++j)
                    acc[i][j] = __builtin_amdgcn_mfma_f32_16x16x32_f16(
                        af[i], bf[j], acc[i][j], 0, 0, 0);
        }

        if (tid < 128) {
            const int r = ntile * 128 + tid;
            sinv[tid] = (r < N_M) ? invn[r] : 0.f;
        }

#pragma unroll 1
        for (int h = 0; h < 2; ++h) {
            __syncthreads();
            if (wr == h) {
#pragma unroll
                for (int fr = 0; fr < 4; ++fr)
#pragma unroll
                    for (int fc = 0; fc < 4; ++fc) {
                        f16x4 v;
#pragma unroll
                        for (int r = 0; r < 4; ++r) v[r] = (_Float16)acc[fr][fc][r];
                        *(f16x4*)&Ss[wc * 64 + fc * 16 + l15][fr * 16 + lg * 4] = v;
                    }
            }
            __syncthreads();

            if (tid < 128) {
                const int base = ntile * 128 + h * 64;
                int nval = N_M - base;
                if (nval > 64) nval = 64;
#pragma unroll 1
                for (int c = 0; c < nval; c += 8) {
                    f16x8 sv = *(const f16x8*)&Ss[tid][c];
                    f32x4 sa = *(const f32x4*)&sinv[h * 64 + c];
                    f32x4 sb = *(const f32x4*)&sinv[h * 64 + c + 4];
                    const int lim = (nval - c >= 8) ? 8 : (nval - c);
                    float s[8];
#pragma unroll
                    for (int j = 0; j < 4; ++j) {
                        s[j]     = (float)sv[j] * sa[j];
                        s[4 + j] = (float)sv[4 + j] * sb[j];
                    }
                    if (lim < 8)
#pragma unroll
                        for (int j = 0; j < 8; ++j)
                            if (j >= lim) s[j] = -INFINITY;
                    float m01 = fmaxf(s[0], s[1]), m23 = fmaxf(s[2], s[3]);
                    float m45 = fmaxf(s[4], s[5]), m67 = fmaxf(s[6], s[7]);
                    float mx = fmaxf(fmaxf(m01, m23), fmaxf(m45, m67));
                    if (mx >= rv[NC - 1]) {
#pragma unroll 1
                        for (int j = 0; j < 8; ++j) {
                            if (j >= lim) break;
                            float cv = s[j]; int ci = base + c + j;
                            if (better(cv, ci, rv[NC - 1], ri[NC - 1])) {
#pragma unroll
                                for (int k = 0; k < NC; ++k) {
                                    bool b = better(cv, ci, rv[k], ri[k]);
                                    float nv = b ? cv : rv[k]; int ni = b ? ci : ri[k];
                                    float ov = b ? rv[k] : cv; int oi = b ? ri[k] : ci;
                                    rv[k] = nv; ri[k] = ni; cv = ov; ci = oi;
                                }
                            }
                        }
                    }
                }
            }
        }
    }

    if (tid < 128) {
        const int qg = qtile * 128 + tid;
        Cand* dst = cand + ((size_t)qg * nsuper + sup) * NC;
#pragma unroll
        for (int k = 0; k < NC; ++k) { Cand c; c.v = rv[k]; c.i = ri[k]; dst[k] = c; }
    }
}

// ---------------------------------------------------------------------------
// Kernel 2: per query, reduce nsuper*16 candidates to global approx top-16.
// ---------------------------------------------------------------------------
__global__ __launch_bounds__(64)
void knn_top16(const Cand* __restrict__ cand, int* __restrict__ top_idx, int ncand)
{
    __shared__ float lv[64][NC];
    __shared__ int   li[64][NC];

    const int q = blockIdx.x;
    const int lane = threadIdx.x;
    const Cand* rowp = cand + (size_t)q * ncand;

    float tv[NC]; int ti[NC];
#pragma unroll
    for (int k = 0; k < NC; ++k) { tv[k] = -INFINITY; ti[k] = 0; }

#pragma unroll 1
    for (int e = lane; e < ncand; e += 64) {
        Cand c = rowp[e];
        if (better(c.v, c.i, tv[NC - 1], ti[NC - 1])) {
            float cv = c.v; int ci = c.i;
#pragma unroll
            for (int k = 0; k < NC; ++k) {
                bool b = better(cv, ci, tv[k], ti[k]);
                float nv = b ? cv : tv[k]; int ni = b ? ci : ti[k];
                float ov = b ? tv[k] : cv; int oi = b ? ti[k] : ci;
                tv[k] = nv; ti[k] = ni; cv = ov; ci = oi;
            }
        }
    }

#pragma unroll
    for (int k = 0; k < NC; ++k) { lv[lane][k] = tv[k]; li[lane][k] = ti[k]; }
    __syncthreads();

    if (lane == 0) {
#pragma unroll 1
        for (int l = 1; l < 64; ++l) {
#pragma unroll 1
            for (int k = 0; k < NC; ++k) {
                float v = lv[l][k]; int i = li[l][k];
                if (!better(v, i, tv[NC - 1], ti[NC - 1])) break;
                float cv = v; int ci = i;
#pragma unroll
                for (int kk = 0; kk < NC; ++kk) {
                    bool b = better(cv, ci, tv[kk], ti[kk]);
                    float nv = b ? cv : tv[kk]; int ni = b ? ci : ti[kk];
                    float ov = b ? tv[kk] : cv; int oi = b ? ti[kk] : ci;
                    tv[kk] = nv; ti[kk] = ni; cv = ov; ci = oi;
                }
            }
        }
#pragma unroll
        for (int k = 0; k < NC; ++k) top_idx[q * NC + k] = ti[k];
    }
}

// ---------------------------------------------------------------------------
// Kernel 3: exact fp64 rescore of the 16 candidates, top-k, gather-average.
// ---------------------------------------------------------------------------
__global__ __launch_bounds__(256)
void knn_rescore(const float* __restrict__ Qm, const float* __restrict__ Mm,
                 const float* __restrict__ Sm, const int* __restrict__ topk_p,
                 const int* __restrict__ top_idx, float* __restrict__ outp)
{
    const int q   = blockIdx.x;
    const int tid = threadIdx.x;
    const int wid = tid >> 6, lane = tid & 63;

    __shared__ double sval[NC];
    __shared__ int    sidx[NC];
    __shared__ int    chosen[NC];

    int k = *topk_p;
    if (k > NC) k = NC;
    if (k < 1)  k = 1;

    const float* qrow = Qm + (size_t)q * D_DIM;
#pragma unroll 1
    for (int ci = wid; ci < NC; ci += 4) {
        int idx = top_idx[q * NC + ci];
        if (idx < 0)    idx = 0;
        if (idx >= N_M) idx = N_M - 1;
        const f32x4* mp = (const f32x4*)(Mm + (size_t)idx * D_DIM) + lane * 4;
        const f32x4* qp = (const f32x4*)qrow + lane * 4;
        double dot = 0.0, ss = 0.0;
#pragma unroll
        for (int j = 0; j < 4; ++j) {
            f32x4 mv = mp[j], qv = qp[j];
#pragma unroll
            for (int u = 0; u < 4; ++u) {
                dot += (double)mv[u] * (double)qv[u];
                ss  += (double)mv[u] * (double)mv[u];
            }
        }
#pragma unroll
        for (int off = 1; off <= 32; off <<= 1) {
            dot += __shfl_xor(dot, off, 64);
            ss  += __shfl_xor(ss, off, 64);
        }
        if (lane == 0) { sval[ci] = ss > 0.0 ? dot / sqrt(ss) : -1e300; sidx[ci] = idx; }
    }
    __syncthreads();

    if (tid == 0) {
        unsigned used = 0;
        for (int j = 0; j < k; ++j) {
            int best = -1;
            for (int i = 0; i < NC; ++i) {
                if (used & (1u << i)) continue;
                if (best < 0 || sval[i] > sval[best] ||
                    (sval[i] == sval[best] && sidx[i] < sidx[best])) best = i;
            }
            used |= 1u << best;
            chosen[j] = sidx[best];
        }
    }
    __syncthreads();

    const int d0 = tid * 4;
    f32x4 a = zero4();
    for (int j = 0; j < k; ++j) {
        f32x4 s4 = *(const f32x4*)(Sm + (size_t)chosen[j] * D_DIM + d0);
        a = a + s4;
    }
    const float inv = 1.0f / (float)k;
    a = a * inv;
    *(f32x4*)(outp + (size_t)q * D_DIM + d0) = a;
}

// ---------------------------------------------------------------------------
// Fallback: round-5 brute force, verbatim (proven: passed, absmax 0.0).
// ---------------------------------------------------------------------------
#define FNC 8
__global__ __launch_bounds__(256)
void knn_all(const float* __restrict__ Qm, const float* __restrict__ Mm,
             const float* __restrict__ Sm, const int* __restrict__ topk_p,
             float* __restrict__ outp)
{
    __shared__ float  qs[D_DIM];
    __shared__ float  wv[4][FNC];
    __shared__ int    wi[4][FNC];
    __shared__ int    cand8[FNC];
    __shared__ double dval[FNC];
    __shared__ int    chosen[FNC];
    __shared__ int    sk;

    const int q    = blockIdx.x;
    const int tid  = threadIdx.x;
    const int wid  = tid >> 6;
    const int lane = tid & 63;

    for (int i = tid; i < D_DIM / 4; i += 256)
        ((f32x4*)qs)[i] = ((const f32x4*)(Qm + (size_t)q * D_DIM))[i];
    __syncthreads();

    float tv[FNC]; int ti[FNC];
#pragma unroll
    for (int k = 0; k < FNC; ++k) { tv[k] = -INFINITY; ti[k] = 0; }

    for (int r = wid; r < N_M; r += 4) {
        const f32x4* mp = (const f32x4*)(Mm + (size_t)r * D_DIM) + lane * 4;
        const f32x4* qp = (const f32x4*)qs + lane * 4;
        float dot = 0.f, ss = 0.f;
#pragma unroll
        for (int j = 0; j < 4; ++j) {
            f32x4 mv = mp[j], qv = qp[j];
#pragma unroll
            for (int u = 0; u < 4; ++u) { dot += mv[u] * qv[u]; ss += mv[u] * mv[u]; }
        }
#pragma unroll
        for (int off = 1; off <= 32; off <<= 1) {
            dot += __shfl_xor(dot, off, 64);
            ss  += __shfl_xor(ss,  off, 64);
        }
        float s = ss > 0.f ? dot * rsqrtf(ss) : -INFINITY;
        if (better(s, r, tv[FNC - 1], ti[FNC - 1])) {
            float cv = s; int ci = r;
#pragma unroll
            for (int k = 0; k < FNC; ++k) {
                bool b = better(cv, ci, tv[k], ti[k]);
                float nv = b ? cv : tv[k]; int ni = b ? ci : ti[k];
                float ov = b ? tv[k] : cv; int oi = b ? ti[k] : ci;
                tv[k] = nv; ti[k] = ni; cv = ov; ci = oi;
            }
        }
    }

    if (lane == 0)
#pragma unroll
        for (int k = 0; k < FNC; ++k) { wv[wid][k] = tv[k]; wi[wid][k] = ti[k]; }
    __syncthreads();

    if (tid == 0) {
        unsigned used = 0;
        for (int j = 0; j < FNC; ++j) {
            float bv = -INFINITY; int bi = 0; int bs = -1;
            for (int s = 0; s < 4 * FNC; ++s) {
                if (used & (1u << s)) continue;
                float v = wv[s >> 3][s & 7]; int i = wi[s >> 3][s & 7];
                if (bs < 0 || better(v, i, bv, bi)) { bv = v; bi = i; bs = s; }
            }
            used |= 1u << bs;
            cand8[j] = bi;
        }
        int kk = *topk_p;
        if (kk < 1) kk = 1;
        if (kk > FNC) kk = FNC;
        sk = kk;
    }
    __syncthreads();

    for (int ci = wid; ci < FNC; ci += 4) {
        int idx = cand8[ci];
        if (idx < 0)     idx = 0;
        if (idx >= N_M)  idx = N_M - 1;
        const f32x4* mp = (const f32x4*)(Mm + (size_t)idx * D_DIM) + lane * 4;
        const f32x4* qp = (const f32x4*)qs + lane * 4;
        double dot = 0.0, ss = 0.0;
#pragma unroll
        for (int j = 0; j < 4; ++j) {
            f32x4 mv = mp[j], qv = qp[j];
#pragma unroll
            for (int u = 0; u < 4; ++u) {
                dot += (double)mv[u] * (double)qv[u];
                ss  += (double)mv[u] * (double)mv[u];
            }
        }
#pragma unroll
        for (int off = 1; off <= 32; off <<= 1) {
            dot += __shfl_xor(dot, off, 64);
            ss  += __shfl_xor(ss, off, 64);
        }
        if (lane == 0) dval[ci] = ss > 0.0 ? dot / sqrt(ss) : -1e300;
    }
    __syncthreads();

    if (tid == 0) {
        int kk = sk;
        unsigned used = 0;
        for (int j = 0; j < kk; ++j) {
            int best = -1;
            for (int i = 0; i < FNC; ++i) {
                if (used & (1u << i)) continue;
                if (best < 0 || dval[i] > dval[best] ||
                    (dval[i] == dval[best] && cand8[i] < cand8[best])) best = i;
            }
            used |= 1u << best;
            chosen[j] = cand8[best];
        }
    }
    __syncthreads();

    const int kk = sk;
    const int d0 = tid * 4;
    f32x4 a = zero4();
    for (int j = 0; j < kk; ++j) {
        f32x4 s4 = *(const f32x4*)(Sm + (size_t)chosen[j] * D_DIM + d0);
        a = a + s4;
    }
    const float inv = 1.0f / (float)kk;
    a = a * inv;
    *(f32x4*)(outp + (size_t)q * D_DIM + d0) = a;
}

// ---------------------------------------------------------------------------
extern "C" void kernel_launch(void* const* d_in, const int* in_sizes, int n_in,
                              void* d_out, int out_size, void* d_ws, size_t ws_size,
                              hipStream_t stream)
{
    (void)in_sizes; (void)n_in; (void)out_size;

    const float* Qm   = (const float*)d_in[0];
    const float* Mm   = (const float*)d_in[1];
    const float* Sm   = (const float*)d_in[2];
    const int*   topk = (const int*)d_in[3];
    float*       outp = (float*)d_out;

    const size_t A511      = 511;
    const size_t mh_bytes  = (((size_t)MPAD * D_DIM * sizeof(_Float16)) + A511) & ~A511;
    const size_t qh_bytes  = (size_t)QPAD * D_DIM * sizeof(_Float16);                 // 4 MiB
    const size_t inv_bytes = ((size_t)N_M * sizeof(float) + A511) & ~A511;
    const size_t ti_bytes  = (((size_t)T_Q * NC * sizeof(int)) + A511) & ~A511;
    const size_t per_sup   = (size_t)QPAD * NC * sizeof(Cand);                        // 256 KiB

    // ---- main path: fp16 prescaled M (needs ~216 MB of workspace) ----
    if (d_ws != nullptr) {
        long long avail = (long long)ws_size
                        - (long long)(mh_bytes + qh_bytes + ti_bytes);
        int ns = avail > 0 ? (int)(avail / (long long)per_sup) : 0;
        if (ns > 64) ns = 64;
        if (ns >= 1) {
            int tpbn = (NTILES + ns - 1) / ns;
            ns = (NTILES + tpbn - 1) / tpbn;

            _Float16* Mh      = (_Float16*)d_ws;
            _Float16* Qh      = (_Float16*)((char*)d_ws + mh_bytes);
            int*      top_idx = (int*)((char*)d_ws + mh_bytes + qh_bytes);
            Cand*     cand    = (Cand*)((char*)d_ws + mh_bytes + qh_bytes + ti_bytes);

            hipLaunchKernelGGL(knn_qcvt, dim3(QPAD * D_DIM / 2048), dim3(256), 0, stream,
                               Qm, Qh);
            hipLaunchKernelGGL(knn_mcvt, dim3(MPAD / 4), dim3(256), 0, stream,
                               Mm, Mh);
            hipLaunchKernelGGL(knn_gemm_select_h, dim3(QTILES * ns), dim3(256), 0, stream,
                               Qh, Mh, cand, tpbn, ns);
            hipLaunchKernelGGL(knn_top16, dim3(T_Q), dim3(64), 0, stream,
                               cand, top_idx, ns * NC);
            hipLaunchKernelGGL(knn_rescore, dim3(T_Q), dim3(256), 0, stream,
                               Qm, Mm, Sm, topk, top_idx, outp);
            return;
        }

        // ---- middle path: round-7 structure (~20 MB of workspace) ----
        avail = (long long)ws_size
              - (long long)(inv_bytes + qh_bytes + ti_bytes);
        ns = avail > 0 ? (int)(avail / (long long)per_sup) : 0;
        if (ns > 64) ns = 64;
        if (ns >= 1) {
            int tpbn = (NTILES + ns - 1) / ns;
            ns = (NTILES + tpbn - 1) / tpbn;

            float*    invn    = (float*)d_ws;
            _Float16* Qh      = (_Float16*)((char*)d_ws + inv_bytes);
            int*      top_idx = (int*)((char*)d_ws + inv_bytes + qh_bytes);
            Cand*     cand    = (Cand*)((char*)d_ws + inv_bytes + qh_bytes + ti_bytes);

            hipLaunchKernelGGL(knn_qcvt, dim3(QPAD * D_DIM / 2048), dim3(256), 0, stream,
                               Qm, Qh);
            hipLaunchKernelGGL(knn_norms, dim3((N_M + 3) / 4), dim3(256), 0, stream,
                               Mm, invn);
            hipLaunchKernelGGL(knn_gemm_select, dim3(QTILES * ns), dim3(256), 0, stream,
                               Qh, Mm, invn, cand, tpbn, ns);
            hipLaunchKernelGGL(knn_top16, dim3(T_Q), dim3(64), 0, stream,
                               cand, top_idx, ns * NC);
            hipLaunchKernelGGL(knn_rescore, dim3(T_Q), dim3(256), 0, stream,
                               Qm, Mm, Sm, topk, top_idx, outp);
            return;
        }
    }

    // ---- last resort: zero-workspace brute force ----
    hipLaunchKernelGGL(knn_all, dim3(T_Q), dim3(256), 0, stream,
                       Qm, Mm, Sm, topk, outp);
}